// Round 5
// baseline (147.905 us; speedup 1.0000x reference)
//
#include <hip/hip_runtime.h>
#include <hip/hip_cooperative_groups.h>

namespace cg = cooperative_groups;

// Phosphene simulator, MI355X — single cooperative kernel.
// ref: 256 discs (r<=15), separable 21-tap truncated Gaussian (sigma=r/3,
// support +-ceil(2*sigma)<=10, reflect pad), threshold 0.05, sum, clamp 1.0,
// max-normalize. Patch support <= 51x51 px.
// R4 lesson: top dispatch is the harness's 268MB 0xAA ws-poison (40us,
// 84% HBM peak — uncontrollable). Controllable cost = 4 launches + image
// round-trips -> fuse into ONE cooperative launch with grid.sync() phases.

#define SIZE   512
#define NPIX   (SIZE * SIZE)
#define H      10
#define KW     21
#define THRESH 0.05f

__global__ __launch_bounds__(256) void fused_k(
    const float* __restrict__ pc, const float* __restrict__ grid,
    float* __restrict__ img, unsigned* __restrict__ mx)
{
  cg::grid_group gg = cg::this_grid();
  const int p = blockIdx.x;   // one block per phosphene; also slice index
  const int t = threadIdx.x;

  __shared__ float vert[51 * 32];  // vertical-blur patch, stride 32
  __shared__ float smax[4];
  __shared__ float snorm;

  // ---- phase 0: zero image (1 float4/thread/block = 1024 floats/block) ----
  ((float4*)img)[p * 256 + t] = make_float4(0.f, 0.f, 0.f, 0.f);
  if (p == 0 && t == 0) *mx = 0u;
  gg.sync();

  // ---- phase 1: render phosphene p, atomicAdd into img ----
  {
    const float x = grid[3 * p + 0];
    const float y = grid[3 * p + 1];
    const float r = grid[3 * p + 2];
    const float b = pc[p];

    // weights: exp(-0.5*(pos/sigma)^2) * (|pos| <= ceil(2*sigma)), normalized
    const float sigma = r / 3.0f;
    const float halfw = ceilf(2.0f * sigma);
    float w[KW];
    float s = 0.0f;
#pragma unroll
    for (int k = 0; k < KW; ++k) {
      float pos = (float)(k - H);
      float wt = (fabsf(pos) <= halfw)
                     ? expf(-0.5f * (pos / sigma) * (pos / sigma))
                     : 0.0f;
      w[k] = wt;
      s += wt;
    }
#pragma unroll
    for (int k = 0; k < KW; ++k) w[k] /= s;

    // pixel i has coordinate c=i+1 -> disc center (x-1, y-1) 0-based
    const float cx = x - 1.0f;
    const float cy = y - 1.0f;
    int icmin = max((int)ceilf(cx - r), 0);
    int icmax = min((int)floorf(cx + r), SIZE - 1);
    int irmin = max((int)ceilf(cy - r), 0);
    int irmax = min((int)floorf(cy + r), SIZE - 1);
    const int ox0 = max(0, icmin - H), ox1 = min(SIZE - 1, icmax + H);
    const int oy0 = max(0, irmin - H), oy1 = min(SIZE - 1, irmax + H);
    const int ncol = icmax - icmin + 1;  // <= 31
    const int nrow = oy1 - oy0 + 1;      // <= 51
    const float r2 = r * r;

    // vertical blur of analytic disc mask, reflect rows at 0/511
    for (int idx = t; idx < nrow * ncol; idx += 256) {
      int cj = idx / ncol;
      int ci = idx - cj * ncol;
      int c  = icmin + ci;
      float dx  = (float)c - cx;
      float dx2 = dx * dx;
      int j = oy0 + cj;
      float acc = 0.0f;
#pragma unroll
      for (int k = 0; k < KW; ++k) {
        int jj = j + (k - H);
        jj = (jj < 0) ? -jj : ((jj > SIZE - 1) ? 2 * (SIZE - 1) - jj : jj);
        float dy = (float)jj - cy;
        acc += (dx2 + dy * dy <= r2) ? w[k] : 0.0f;
      }
      vert[cj * 32 + ci] = acc;
    }
    __syncthreads();

    // horizontal blur (reflect cols; vert(reflected col)==vert(col)),
    // scale by brightness, threshold, accumulate
    const int nox = ox1 - ox0 + 1;  // <= 51
    for (int idx = t; idx < nrow * nox; idx += 256) {
      int cj = idx / nox;
      int ci = idx - cj * nox;
      int i = ox0 + ci;
      int j = oy0 + cj;
      float acc = 0.0f;
#pragma unroll
      for (int k = 0; k < KW; ++k) {
        int ii = i + (k - H);
        ii = (ii < 0) ? -ii : ((ii > SIZE - 1) ? 2 * (SIZE - 1) - ii : ii);
        int cc = ii - icmin;
        if ((unsigned)cc < (unsigned)ncol) acc += w[k] * vert[cj * 32 + cc];
      }
      float val = acc * b;
      if (val >= THRESH) atomicAdd(&img[j * SIZE + i], val);
    }
  }
  gg.sync();

  // ---- phase 2: block max over own slice (keep data in registers) ----
  float4 v = ((float4*)img)[p * 256 + t];
  {
    float m = fmaxf(fmaxf(v.x, v.y), fmaxf(v.z, v.w));
#pragma unroll
    for (int off = 32; off > 0; off >>= 1)
      m = fmaxf(m, __shfl_down(m, off, 64));
    if ((t & 63) == 0) smax[t >> 6] = m;
    __syncthreads();
    if (t == 0) {
      m = fmaxf(fmaxf(smax[0], smax[1]), fmaxf(smax[2], smax[3]));
      // all values >= 0 -> float ordering == uint-bit ordering
      atomicMax(mx, __float_as_uint(m));
    }
  }
  gg.sync();

  // ---- phase 3: fused clip+normalize of register-held slice ----
  // max(min(img,1)) == min(max_raw,1) since clamp is monotone.
  if (t == 0) {
    float m = fminf(__uint_as_float(*(volatile unsigned*)mx), 1.0f);
    snorm = (m > 0.0f) ? 1.0f / m : 1.0f;
  }
  __syncthreads();
  {
    float inv = snorm;
    v.x = fminf(v.x, 1.0f) * inv;
    v.y = fminf(v.y, 1.0f) * inv;
    v.z = fminf(v.z, 1.0f) * inv;
    v.w = fminf(v.w, 1.0f) * inv;
    ((float4*)img)[p * 256 + t] = v;
  }
}

extern "C" void kernel_launch(void* const* d_in, const int* in_sizes, int n_in,
                              void* d_out, int out_size, void* d_ws, size_t ws_size,
                              hipStream_t stream)
{
  const float* pc   = (const float*)d_in[0];  // phoscoding (256,)
  const float* grd  = (const float*)d_in[1];  // grid (256,3): x,y,r
  float* img   = (float*)d_out;               // (1,1,512,512) f32
  unsigned* mx = (unsigned*)d_ws;             // 4 bytes: raw-max bits

  void* args[] = {(void*)&pc, (void*)&grd, (void*)&img, (void*)&mx};
  hipLaunchCooperativeKernel((const void*)fused_k, dim3(256), dim3(256),
                             args, 0, stream);
}